// Round 2
// baseline (67.956 us; speedup 1.0000x reference)
//
#include <hip/hip_runtime.h>

// OneHotEncoder: per-row histogram of tokens, skipping pad_idx=0.
// tokens: [B=256, T=2048] int32 ; out: [B, VOCAB=32000] float32.
//
// R1 lesson: 1 block/CU (256 blocks, 64KB LDS) left the chip ~8% occupied;
// kernel was latency-bound, not BW-bound (harness fills hit 6.2 TB/s).
// R2: vocab-sliced blocks. Grid = B rows x 8 slices = 2048 blocks of 256
// threads (8 blocks/CU = 32 waves/CU, full occupancy), 8KB LDS per block.
// Each block scans its whole row (8KB, L2/L3-cached across slices) and
// histograms only its 4000-bin slice (packed 2x16-bit counts), then streams
// the slice out with coalesced float4 stores (each output byte written once).

#define VOCAB 32000
#define SLICES 8
#define SLICE_BINS (VOCAB / SLICES)   // 4000
#define BLOCK 256

__global__ __launch_bounds__(BLOCK)
void OneHotEncoder_43052752175267_kernel(const int* __restrict__ tokens,
                                         float* __restrict__ out,
                                         int T) {
    // Packed: hist[i] = counts for slice-local bins 2i (lo16) / 2i+1 (hi16).
    // Max count = T = 2048 < 65536 -> no carry into the neighboring half.
    __shared__ __align__(16) unsigned int hist[SLICE_BINS / 2];  // 2000 u32 = 8000 B

    const int slice = blockIdx.x;
    const int row   = blockIdx.y;
    const int tid   = threadIdx.x;
    const int base  = slice * SLICE_BINS;

    // --- Phase 1: zero LDS slice (uint4) ---
    uint4* h4 = (uint4*)hist;
    const uint4 z = make_uint4(0u, 0u, 0u, 0u);
    for (int i = tid; i < SLICE_BINS / 8; i += BLOCK)  // 500 uint4
        h4[i] = z;
    __syncthreads();

    // --- Phase 2: scan row tokens (int4 vector loads), count ours ---
    const int4* trow4 = (const int4*)(tokens + (long long)row * T);
    for (int i = tid; i < T / 4; i += BLOCK) {  // 512 int4, 2 iters/thread
        int4 tk = trow4[i];
        #pragma unroll
        for (int j = 0; j < 4; ++j) {
            int tok = (j == 0) ? tk.x : (j == 1) ? tk.y : (j == 2) ? tk.z : tk.w;
            unsigned int local = (unsigned int)(tok - base);
            if (local < SLICE_BINS && tok != 0)
                atomicAdd(&hist[local >> 1], 1u << ((local & 1) << 4));
        }
    }
    __syncthreads();

    // --- Phase 3: unpack and stream out slice, coalesced float4 ---
    float4* o4 = (float4*)(out + (long long)row * VOCAB + base);
    const uint2* h2 = (const uint2*)hist;
    for (int i = tid; i < SLICE_BINS / 4; i += BLOCK) {  // 1000 float4
        uint2 h = h2[i];
        float4 f;
        f.x = (float)(h.x & 0xFFFFu);
        f.y = (float)(h.x >> 16);
        f.z = (float)(h.y & 0xFFFFu);
        f.w = (float)(h.y >> 16);
        o4[i] = f;
    }
}

extern "C" void kernel_launch(void* const* d_in, const int* in_sizes, int n_in,
                              void* d_out, int out_size, void* d_ws, size_t ws_size,
                              hipStream_t stream) {
    const int* tokens = (const int*)d_in[0];
    // d_in[1] (lengths) is unused by the reference computation.
    const int B = in_sizes[1];           // 256 (one length per row)
    const int T = in_sizes[0] / B;       // 2048
    float* out = (float*)d_out;

    OneHotEncoder_43052752175267_kernel<<<dim3(SLICES, B), dim3(BLOCK), 0, stream>>>(
        tokens, out, T);
}

// Round 4
// 67.824 us; speedup vs baseline: 1.0019x; 1.0019x over previous
//
#include <hip/hip_runtime.h>

// OneHotEncoder: per-row histogram of tokens, skipping pad_idx=0.
// tokens: [B=256, T=2048] int32 ; out: [B, VOCAB=32000] float32.
//
// Structure (R2): vocab-sliced blocks. Grid = 8 slices x 256 rows = 2048
// blocks of 256 threads (8 blocks/CU = 32 waves/CU), 8KB LDS packed 2x16-bit
// histogram per block. Each block scans its row (L2-cached across slices),
// counts its 4000-bin slice, streams the slice out once, coalesced.
//
// R4 delta: nontemporal stores via native clang ext_vector_type (the HIP
// float4 struct is rejected by __builtin_nontemporal_store). Output (33 MB)
// is never re-read -> skip L2 allocation.
// R1->R2 lesson: bench dur_us (~66us) is dominated by harness poison fills
// (268 MB/replay visible in rocprof at 78% HBM peak); kernel itself is below
// the top-5 cutoff. Kernel structural floor: 2 MB read + 33 MB write ~5.5us.

#define VOCAB 32000
#define SLICES 8
#define SLICE_BINS (VOCAB / SLICES)   // 4000
#define BLOCK 256

typedef float f32x4 __attribute__((ext_vector_type(4)));

__global__ __launch_bounds__(BLOCK)
void OneHotEncoder_43052752175267_kernel(const int* __restrict__ tokens,
                                         float* __restrict__ out,
                                         int T) {
    // Packed: hist[i] = counts for slice-local bins 2i (lo16) / 2i+1 (hi16).
    // Max count = T = 2048 < 65536 -> no carry into the neighboring half.
    __shared__ __align__(16) unsigned int hist[SLICE_BINS / 2];  // 2000 u32 = 8000 B

    const int slice = blockIdx.x;
    const int row   = blockIdx.y;
    const int tid   = threadIdx.x;
    const int base  = slice * SLICE_BINS;

    // --- Phase 1: zero LDS slice (uint4) ---
    uint4* h4 = (uint4*)hist;
    const uint4 z = make_uint4(0u, 0u, 0u, 0u);
    for (int i = tid; i < SLICE_BINS / 8; i += BLOCK)  // 500 uint4
        h4[i] = z;
    __syncthreads();

    // --- Phase 2: scan row tokens (int4 vector loads), count ours ---
    const int4* trow4 = (const int4*)(tokens + (long long)row * T);
    for (int i = tid; i < T / 4; i += BLOCK) {  // 512 int4, 2 iters/thread
        int4 tk = trow4[i];
        #pragma unroll
        for (int j = 0; j < 4; ++j) {
            int tok = (j == 0) ? tk.x : (j == 1) ? tk.y : (j == 2) ? tk.z : tk.w;
            unsigned int local = (unsigned int)(tok - base);
            if (local < SLICE_BINS && tok != 0)
                atomicAdd(&hist[local >> 1], 1u << ((local & 1) << 4));
        }
    }
    __syncthreads();

    // --- Phase 3: unpack and stream out slice, nontemporal coalesced 16B stores ---
    f32x4* o4 = (f32x4*)(out + (long long)row * VOCAB + base);
    const uint2* h2 = (const uint2*)hist;
    for (int i = tid; i < SLICE_BINS / 4; i += BLOCK) {  // 1000 stores
        uint2 h = h2[i];
        f32x4 f;
        f.x = (float)(h.x & 0xFFFFu);
        f.y = (float)(h.x >> 16);
        f.z = (float)(h.y & 0xFFFFu);
        f.w = (float)(h.y >> 16);
        __builtin_nontemporal_store(f, &o4[i]);
    }
}

extern "C" void kernel_launch(void* const* d_in, const int* in_sizes, int n_in,
                              void* d_out, int out_size, void* d_ws, size_t ws_size,
                              hipStream_t stream) {
    const int* tokens = (const int*)d_in[0];
    // d_in[1] (lengths) is unused by the reference computation.
    const int B = in_sizes[1];           // 256 (one length per row)
    const int T = in_sizes[0] / B;       // 2048
    float* out = (float*)d_out;

    OneHotEncoder_43052752175267_kernel<<<dim3(SLICES, B), dim3(BLOCK), 0, stream>>>(
        tokens, out, T);
}